// Round 1
// baseline (116.570 us; speedup 1.0000x reference)
//
#include <hip/hip_runtime.h>
#include <math.h>

// Problem constants
#define H_IN   256
#define W_IN   256
#define CIN    3
#define COUT   128
#define NB     8
#define KS     3
#define H_OUT  254
#define W_OUT  254

#define ROW_F   (W_IN * CIN)   // 768 floats per input row
#define LDS_ROW 780            // padded: worst read index (255+2)*3+2 = 773
#define PIX_PER_BLK 8
#define NTILES  ((W_OUT + PIX_PER_BLK - 1) / PIX_PER_BLK)  // 32

__global__ __launch_bounds__(256, 2)
void conv_meanvar_kernel(const float* __restrict__ in,
                         const float* __restrict__ w_mu,
                         const float* __restrict__ w_sigma,
                         float* __restrict__ out)
{
    __shared__ float in_lds[KS][LDS_ROW];

    const int h   = blockIdx.x;        // 0..253
    const int n   = blockIdx.y;        // 0..7
    const int tid = threadIdx.x;       // 0..255
    const int px  = tid >> 5;          // pixel slot within tile, 0..7
    const int c4  = (tid & 31) * 4;    // channel quad base, 0..124

    // ---- stage 3 contiguous input rows (h..h+2) into LDS: 2304 floats ----
    const float* src = in + (size_t)(n * H_IN + h) * ROW_F;
    #pragma unroll
    for (int k = 0; k < 9; ++k) {
        int idx = tid + k * 256;               // 0..2303
        int r   = idx / ROW_F;                 // 0..2
        int col = idx - r * ROW_F;
        in_lds[r][col] = src[idx];
    }

    // ---- weights for my 4 channels into registers: 27 x float4 ----
    float4 wr[27];
    #pragma unroll
    for (int kk = 0; kk < 27; ++kk)
        wr[kk] = *reinterpret_cast<const float4*>(w_mu + kk * COUT + c4);

    // ---- softplus(w_sigma) for my 4 channels ----
    float4 ws = *reinterpret_cast<const float4*>(w_sigma + c4);
    float4 sp;
    sp.x = log1pf(expf(ws.x));
    sp.y = log1pf(expf(ws.y));
    sp.z = log1pf(expf(ws.z));
    sp.w = log1pf(expf(ws.w));

    __syncthreads();

    const size_t pix_base   = (size_t)(n * H_OUT + h) * W_OUT;
    const size_t sigma_off  = (size_t)NB * H_OUT * W_OUT * COUT;  // 66,064,384
    float* const out_sigma  = out + sigma_off;

    for (int it = 0; it < NTILES; ++it) {
        const int w = it * PIX_PER_BLK + px;   // up to 255; guarded at store
        const int base = w * CIN;

        float4 mu = {0.f, 0.f, 0.f, 0.f};
        float sumsq = 0.f;

        #pragma unroll
        for (int kh = 0; kh < KS; ++kh) {
            #pragma unroll
            for (int kw = 0; kw < KS; ++kw) {
                #pragma unroll
                for (int ci = 0; ci < CIN; ++ci) {
                    const float x = in_lds[kh][base + kw * CIN + ci];
                    const int kk = (kh * KS + kw) * CIN + ci;
                    mu.x  = fmaf(x, wr[kk].x, mu.x);
                    mu.y  = fmaf(x, wr[kk].y, mu.y);
                    mu.z  = fmaf(x, wr[kk].z, mu.z);
                    mu.w  = fmaf(x, wr[kk].w, mu.w);
                    sumsq = fmaf(x, x, sumsq);
                }
            }
        }

        if (w < W_OUT) {
            const size_t o = (pix_base + w) * COUT + c4;
            *reinterpret_cast<float4*>(out + o) = mu;
            float4 sg;
            sg.x = sumsq * sp.x;
            sg.y = sumsq * sp.y;
            sg.z = sumsq * sp.z;
            sg.w = sumsq * sp.w;
            *reinterpret_cast<float4*>(out_sigma + o) = sg;
        }
    }
}

extern "C" void kernel_launch(void* const* d_in, const int* in_sizes, int n_in,
                              void* d_out, int out_size, void* d_ws, size_t ws_size,
                              hipStream_t stream)
{
    const float* in      = (const float*)d_in[0];
    const float* w_mu    = (const float*)d_in[1];
    const float* w_sigma = (const float*)d_in[2];
    float* out           = (float*)d_out;

    dim3 grid(H_OUT, NB);   // 254 x 8 blocks, one output row each
    dim3 block(256);
    conv_meanvar_kernel<<<grid, block, 0, stream>>>(in, w_mu, w_sigma, out);
}

// Round 2
// 114.465 us; speedup vs baseline: 1.0184x; 1.0184x over previous
//
#include <hip/hip_runtime.h>
#include <hip/hip_fp16.h>
#include <math.h>

// Problem constants
#define H_IN   256
#define W_IN   256
#define CIN    3
#define COUT   128
#define NB     8
#define KS     3
#define H_OUT  254
#define W_OUT  254
#define ROW_F  (W_IN * CIN)          // 768 floats per input row

// v_fma_mix_f32: acc(f32) += f16(half of wpk) * x(f32)
#define FMA_MIX_LO(acc, wp, xv) \
    asm("v_fma_mix_f32 %0, %1, %2, %0 op_sel:[0,0,0] op_sel_hi:[1,0,0]" \
        : "+v"(acc) : "v"(wp), "v"(xv))
#define FMA_MIX_HI(acc, wp, xv) \
    asm("v_fma_mix_f32 %0, %1, %2, %0 op_sel:[1,0,0] op_sel_hi:[1,0,0]" \
        : "+v"(acc) : "v"(wp), "v"(xv))

__global__ __launch_bounds__(256, 4)
void conv_meanvar_kernel(const float* __restrict__ in,
                         const float* __restrict__ w_mu,
                         const float* __restrict__ w_sigma,
                         float* __restrict__ out)
{
    // 3 input rows, flat & contiguous (2304 floats) + slack for the guarded
    // tail pixels (reads past row end are discarded by the store guard).
    __shared__ float lds[3 * ROW_F + 32];

    const int h   = blockIdx.x;       // 0..253
    const int n   = blockIdx.y;       // 0..7
    const int tid = threadIdx.x;      // 0..255
    const int px  = tid >> 5;         // pixel-group slot 0..7 (4 pixels each)
    const int c4  = (tid & 31) * 4;   // channel quad base 0..124

    // ---- stage rows h..h+2 (2304 floats) via aligned float4: 144 thr x 4 ----
    const float* src = in + (size_t)(n * H_IN + h) * ROW_F;   // 16B-aligned
    if (tid < 144) {
        const float4* s4 = reinterpret_cast<const float4*>(src) + tid * 4;
        float4* d4 = reinterpret_cast<float4*>(lds) + tid * 4;
        d4[0] = s4[0]; d4[1] = s4[1]; d4[2] = s4[2]; d4[3] = s4[3];
    }

    // ---- weights for my 4 channels -> 27 packed-f16 pairs (54 VGPRs) ----
    unsigned int wpk[27][2];
    #pragma unroll
    for (int kk = 0; kk < 27; ++kk) {
        float4 w = *reinterpret_cast<const float4*>(w_mu + kk * COUT + c4);
        wpk[kk][0] = (unsigned int)__half_as_ushort(__float2half(w.x))
                   | ((unsigned int)__half_as_ushort(__float2half(w.y)) << 16);
        wpk[kk][1] = (unsigned int)__half_as_ushort(__float2half(w.z))
                   | ((unsigned int)__half_as_ushort(__float2half(w.w)) << 16);
    }

    // ---- softplus(w_sigma) for my 4 channels (fp32) ----
    float4 ws = *reinterpret_cast<const float4*>(w_sigma + c4);
    float sp[4];
    sp[0] = log1pf(expf(ws.x));
    sp[1] = log1pf(expf(ws.y));
    sp[2] = log1pf(expf(ws.z));
    sp[3] = log1pf(expf(ws.w));

    __syncthreads();

    const size_t pix_base = (size_t)(n * H_OUT + h) * W_OUT;
    float* const out_sig  = out + (size_t)NB * H_OUT * W_OUT * COUT;

    #pragma unroll 1
    for (int it = 0; it < 8; ++it) {
        const int p0 = it * 32 + px * 4;      // first of my 4 pixels (mult of 4)

        float mu[4][4];
        float ss[4];
        #pragma unroll
        for (int j = 0; j < 4; ++j) {
            ss[j] = 0.f;
            mu[j][0] = mu[j][1] = mu[j][2] = mu[j][3] = 0.f;
        }

        #pragma unroll
        for (int kh = 0; kh < KS; ++kh) {
            // 20 floats cover the 4 windows of this row: offsets provably
            // 16B-aligned (768*kh + 96*it + 12*px, all multiples of 4 floats)
            const float4* rq = reinterpret_cast<const float4*>(
                                   &lds[kh * ROW_F + p0 * 3]);
            float r[20];
            *reinterpret_cast<float4*>(&r[0])  = rq[0];
            *reinterpret_cast<float4*>(&r[4])  = rq[1];
            *reinterpret_cast<float4*>(&r[8])  = rq[2];
            *reinterpret_cast<float4*>(&r[12]) = rq[3];
            *reinterpret_cast<float4*>(&r[16]) = rq[4];

            #pragma unroll
            for (int j = 0; j < 4; ++j) {
                #pragma unroll
                for (int q = 0; q < 9; ++q) {
                    const float x = r[j * 3 + q];
                    const int kk = kh * 9 + q;
                    FMA_MIX_LO(mu[j][0], wpk[kk][0], x);
                    FMA_MIX_HI(mu[j][1], wpk[kk][0], x);
                    FMA_MIX_LO(mu[j][2], wpk[kk][1], x);
                    FMA_MIX_HI(mu[j][3], wpk[kk][1], x);
                    ss[j] = fmaf(x, x, ss[j]);
                }
            }
        }

        #pragma unroll
        for (int j = 0; j < 4; ++j) {
            const int p = p0 + j;
            if (p < W_OUT) {
                const size_t o = (pix_base + p) * COUT + c4;
                float4 m = {mu[j][0], mu[j][1], mu[j][2], mu[j][3]};
                *reinterpret_cast<float4*>(out + o) = m;
                float4 sg = {ss[j] * sp[0], ss[j] * sp[1],
                             ss[j] * sp[2], ss[j] * sp[3]};
                *reinterpret_cast<float4*>(out_sig + o) = sg;
            }
        }
    }
}

extern "C" void kernel_launch(void* const* d_in, const int* in_sizes, int n_in,
                              void* d_out, int out_size, void* d_ws, size_t ws_size,
                              hipStream_t stream)
{
    const float* in      = (const float*)d_in[0];
    const float* w_mu    = (const float*)d_in[1];
    const float* w_sigma = (const float*)d_in[2];
    float* out           = (float*)d_out;

    dim3 grid(H_OUT, NB);   // one output row per block
    dim3 block(256);
    conv_meanvar_kernel<<<grid, block, 0, stream>>>(in, w_mu, w_sigma, out);
}